// Round 19
// baseline (184.265 us; speedup 1.0000x reference)
//
#include <hip/hip_runtime.h>
#include <hip/hip_bf16.h>

typedef unsigned short u16;
typedef float f32x4 __attribute__((ext_vector_type(4)));
typedef float f32x16 __attribute__((ext_vector_type(16)));
typedef __bf16 bf16x8 __attribute__((ext_vector_type(8)));
typedef _Float16 half8 __attribute__((ext_vector_type(8)));
typedef u16 u16x4 __attribute__((ext_vector_type(4)));
typedef u16 u16x8 __attribute__((ext_vector_type(8)));

#define NPIX 4096
#define CDIM 512
#define LOG2E 1.4426950408889634f

static __device__ __forceinline__ u16 f2bf(float f) {
  return __builtin_bit_cast(u16, (__bf16)f);
}
static __device__ __forceinline__ float bf2f(u16 u) {
  unsigned int v = ((unsigned int)u) << 16;
  return __builtin_bit_cast(float, v);
}
static __device__ __forceinline__ u16 f2h(float f) {
  return __builtin_bit_cast(u16, (_Float16)f);
}
static __device__ __forceinline__ f32x16 zero16() {
  f32x16 z;
#pragma unroll
  for (int i = 0; i < 16; ++i) z[i] = 0.0f;
  return z;
}
static __device__ __forceinline__ f32x16 mfma_bf(bf16x8 a, bf16x8 b, f32x16 c) {
  return __builtin_amdgcn_mfma_f32_32x32x16_bf16(a, b, c, 0, 0, 0);
}
static __device__ __forceinline__ f32x16 mfma_h32(half8 a, half8 b, f32x16 c) {
  return __builtin_amdgcn_mfma_f32_32x32x16_f16(a, b, c, 0, 0, 0);
}

// ---------------------------------------------------------------------------
// Kernel 1: fused QKV projection — byte-identical to R16-R18 (validated).
// ---------------------------------------------------------------------------
__global__ __launch_bounds__(640, 3) void proj_kernel(
    const float* __restrict__ x,
    const float* __restrict__ Wq, const float* __restrict__ bq,
    const float* __restrict__ Wk, const float* __restrict__ bk,
    const float* __restrict__ Wv, const float* __restrict__ bv,
    u16* __restrict__ qh, u16* __restrict__ kh, u16* __restrict__ vv)
{
  const int b = blockIdx.y;
  const int nbase = blockIdx.x * 64;
  const int tid = threadIdx.x;
  const int w = tid >> 6;
  const int lane = tid & 63;
  const int lhi = lane >> 5, llo = lane & 31;

  __shared__ float xs[64 * 36];  // [n][k] fp32, +4 pad per row, 9.2 KB

  const float* xb = x + (size_t)b * CDIM * NPIX + nbase;

  const float* wrow[2];
#pragma unroll
  for (int rb = 0; rb < 2; ++rb) {
    int row = 64 * w + 32 * rb + llo;
    wrow[rb] = (row < 64) ? (Wq + (size_t)row * CDIM)
             : (row < 128) ? (Wk + (size_t)(row - 64) * CDIM)
                           : (Wv + (size_t)(row - 128) * CDIM);
  }

  f32x16 acc[2][2];
  acc[0][0] = zero16(); acc[0][1] = zero16();
  acc[1][0] = zero16(); acc[1][1] = zero16();

  for (int ks2 = 0; ks2 < 16; ++ks2) {
    __syncthreads();
    if (tid < 512) {
      int r = tid >> 4, ci = (tid & 15) << 2;
      f32x4 v4 = *(const f32x4*)&xb[(size_t)(ks2 * 32 + r) * NPIX + ci];
#pragma unroll
      for (int d = 0; d < 4; ++d) xs[(ci + d) * 36 + r] = v4[d];
    }
    __syncthreads();

#pragma unroll
    for (int kk = 0; kk < 2; ++kk) {
      const int ksoff = ks2 * 32 + kk * 16;
      half8 af[2];
#pragma unroll
      for (int rb = 0; rb < 2; ++rb) {
        const float* wp = wrow[rb] + ksoff + 8 * lhi;
        f32x4 w0 = *(const f32x4*)(wp);
        f32x4 w1 = *(const f32x4*)(wp + 4);
#pragma unroll
        for (int j = 0; j < 4; ++j) {
          af[rb][j] = (_Float16)w0[j];
          af[rb][4 + j] = (_Float16)w1[j];
        }
      }
      half8 bfr[2];
#pragma unroll
      for (int cb = 0; cb < 2; ++cb) {
        int n = 32 * cb + llo;
        const float* xp = &xs[n * 36 + kk * 16 + 8 * lhi];
        f32x4 x0 = *(const f32x4*)(xp);
        f32x4 x1 = *(const f32x4*)(xp + 4);
#pragma unroll
        for (int j = 0; j < 4; ++j) {
          bfr[cb][j] = (_Float16)x0[j];
          bfr[cb][4 + j] = (_Float16)x1[j];
        }
      }
#pragma unroll
      for (int rb = 0; rb < 2; ++rb)
#pragma unroll
        for (int cb = 0; cb < 2; ++cb)
          acc[rb][cb] = mfma_h32(af[rb], bfr[cb], acc[rb][cb]);
    }
  }

  // Epilogue: C/D layout col = lane&31 (n), row = (r&3)+8*(r>>2)+4*lhi.
#pragma unroll
  for (int rb = 0; rb < 2; ++rb) {
#pragma unroll
    for (int cb = 0; cb < 2; ++cb) {
      int n = nbase + 32 * cb + llo;
#pragma unroll
      for (int gq = 0; gq < 4; ++gq) {
        int dr0 = 8 * gq + 4 * lhi;
        float vals[4];
#pragma unroll
        for (int jj = 0; jj < 4; ++jj) {
          int Mrow = 64 * w + 32 * rb + dr0 + jj;
          float bias = (Mrow < 64) ? bq[Mrow] : (Mrow < 128) ? bk[Mrow - 64] : bv[Mrow - 128];
          vals[jj] = acc[rb][cb][4 * gq + jj] + bias;
        }
        if (w == 0) {  // q: single fp16, pre-scaled by log2(e); [b][n][64]
          u16x4 hq;
#pragma unroll
          for (int jj = 0; jj < 4; ++jj) hq[jj] = f2h(vals[jj] * LOG2E);
          size_t off = ((size_t)b * NPIX + n) * 64 + 32 * rb + dr0;
          *(u16x4*)(qh + off) = hq;
        } else if (w == 1) {  // k: fp16, fragment layout
          u16x4 hk;
#pragma unroll
          for (int jj = 0; jj < 4; ++jj) hk[jj] = f2h(vals[jj]);
          int T = n >> 7, kq = (n >> 5) & 3, lf = n & 31;
          int sf = 2 * rb + (gq >> 1), lh = gq & 1;
          size_t F = (((size_t)b * 32 + T) * 4 + kq) * 4 + sf;
          *(u16x4*)(kh + F * 512 + (32 * lh + lf) * 8 + 4 * lhi) = hk;
        } else {  // v: bf16, fragment layout
          int T = n >> 7, s = (n >> 4) & 7, lh = (n >> 3) & 1, jn = n & 7;
#pragma unroll
          for (int jj = 0; jj < 4; ++jj) {
            int c = 64 * w - 128 + 32 * rb + dr0 + jj;
            size_t F = ((((size_t)b * 2 + (c >> 8)) * 8 + ((c >> 5) & 7)) * 32 + T) * 8 + s;
            vv[F * 512 + (32 * lh + (c & 31)) * 8 + jn] = f2bf(vals[jj]);
          }
        }
      }
    }
  }
}

// ---------------------------------------------------------------------------
// Kernel 2: attention — R18's validated bodies, LDS trimmed to 25.8 KB so
// TWO 1024-thr blocks can co-schedule per CU (2048 thr = HW max; 32 waves x
// 64 VGPR = exactly the register file; 2 x 25.8 KB < 64 KB empirical LDS
// budget). P double-buffered (was triple) with a 1-ahead S cadence: phase t,
// group (t&1) builds tile t+1 into P[(t+1)&1] (kf loaded 2 phases earlier
// via the LOADK(t+3) chain); PV consumes P[t&1] with V direct-from-global.
// If co-residency fires, block B's waves fill block A's barrier/latency
// gaps — the first real 32-wave/CU configuration of this session.
// ---------------------------------------------------------------------------

#define LOADK(T) do {                                                         \
  size_t F_ = (((size_t)batch * 32 + ((T) >> 1)) * 4                          \
               + (2 * ((T) & 1) + kq)) * 4;                                   \
  const u16* kp_ = kh + F_ * 512 + (size_t)lane * 8;                          \
  _Pragma("unroll") for (int s_ = 0; s_ < 4; ++s_)                            \
    kf[s_] = *(const half8*)(kp_ + s_ * 512);                                 \
} while (0)

// R15/R18's exact S body: Qs slot-major reads, P row-major 128B + (row&7)<<4.
#define S_PHASE(PB) do {                                                      \
  f32x16 sacc_ = zero16();                                                    \
  _Pragma("unroll") for (int s_ = 0; s_ < 4; ++s_) {                          \
    half8 qf_ = *(const half8*)(Qs + (2 * s_ + lhi) * 1024                    \
                                + (32 * rb_s + llo) * 16);                    \
    sacc_ = mfma_h32(qf_, kf[s_], sacc_);                                     \
  }                                                                           \
  _Pragma("unroll") for (int r_ = 0; r_ < 16; ++r_) {                         \
    float p_ = __builtin_amdgcn_exp2f(sacc_[r_]);                             \
    u16 pb_ = f2bf(p_);                                                       \
    l_part[r_] += bf2f(pb_);                                                  \
    int row_ = 32 * rb_s + (r_ & 3) + 8 * (r_ >> 2) + 4 * lhi;                \
    int byt_ = (row_ * 128 + (32 * kq + llo) * 2) ^ ((row_ & 7) << 4);        \
    *(u16*)((PB) + byt_) = pb_;                                               \
  }                                                                           \
} while (0)

// V fragments for 64-key tile T, wave w's 32 channels: 4 x b128, coalesced.
#define PVLOADV(T) do {                                                       \
  size_t F0_ = (size_t)(bc8 + w) * 256                                        \
               + (size_t)(((T) >> 1) * 8 + 4 * ((T) & 1));                    \
  const u16* g_ = vv + F0_ * 512 + (size_t)lane * 8;                          \
  vf[0] = *(const bf16x8*)(g_);                                               \
  vf[1] = *(const bf16x8*)(g_ + 512);                                         \
  vf[2] = *(const bf16x8*)(g_ + 1024);                                        \
  vf[3] = *(const bf16x8*)(g_ + 1536);                                        \
} while (0)

// R15/R18's exact PV P-read body, B operand from vf registers.
#define PV_PHASE(PB) do {                                                     \
  _Pragma("unroll") for (int s_ = 0; s_ < 4; ++s_) {                          \
    int by0_ = (llo * 128 + (16 * s_ + 8 * lhi) * 2) ^ ((llo & 7) << 4);      \
    bf16x8 pa0_ = *(const bf16x8*)((PB) + by0_);                              \
    bf16x8 pa1_ = *(const bf16x8*)((PB) + by0_ + 4096);                       \
    acc0 = mfma_bf(pa0_, vf[s_], acc0);                                       \
    acc1 = mfma_bf(pa1_, vf[s_], acc1);                                       \
  }                                                                           \
} while (0)

__global__ __launch_bounds__(1024) void attn_kernel(
    const u16* __restrict__ qh, const u16* __restrict__ kh,
    const u16* __restrict__ vv,
    const float* __restrict__ x, const float* __restrict__ gamma,
    float* __restrict__ out)
{
  const int bid = blockIdx.x;
  const int sw = ((bid & 7) << 6) | (bid >> 3);  // bijective, 512 = 8*64
  const int batch = sw >> 7;
  const int chhalf = (sw >> 6) & 1;
  const int qbase = (sw & 63) * 64;
  const int tid = threadIdx.x;
  const int w = tid >> 6;             // 0-7 PV; 8-11 S grp0; 12-15 S grp1
  const int lane = tid & 63;
  const int lhi = lane >> 5, llo = lane & 31;
  const bool isPV = (w < 8);
  const int grp = (w >= 12) ? 1 : 0;
  const int swv = (w - 8) & 3;
  const int rb_s = swv & 1;           // S row half (q 0-31 / 32-63)
  const int kq = swv >> 1;            // S key block (0..1) in 64-key tile
  const int bc8 = (batch * 2 + chhalf) * 8;

  __shared__ alignas(16) char Psm[16384];   // 2 x [64 q rows x 128 B] bf16
  __shared__ alignas(16) char Qs[8192];     // [d8][64 q] x 16 B, slot-major
  __shared__ float lred[64][4];
  __shared__ alignas(16) float rl_lds[64];

  f32x16 acc0 = zero16(), acc1 = zero16();
  float l_part[16];
#pragma unroll
  for (int r = 0; r < 16; ++r) l_part[r] = 0.0f;
  half8 kf[4];
  bf16x8 vf[4];

  // Prologue A: grp0 fills Qs + LOADK(0); grp1 LOADK(2).
  if (!isPV) {
    if (grp == 0) {
#pragma unroll
      for (int j = 0; j < 2; ++j) {
        int idx = swv * 128 + j * 64 + lane;   // 0..511
        int d8 = idx & 7, row = idx >> 3;
        *(u16x8*)(Qs + d8 * 1024 + row * 16) =
            *(const u16x8*)(qh + ((size_t)batch * NPIX + qbase + row) * 64 + d8 * 8);
      }
      LOADK(0);
    } else {
      LOADK(2);
    }
  }
  __syncthreads();
  // Prologue B: grp0 builds tile 0 -> P[0] (kf = K(0)), then LOADK(1).
  if (!isPV && grp == 0) { S_PHASE(Psm); LOADK(1); }
  __syncthreads();

  // Main loop: phase t: PV loads V(t) (issue-early) then consumes P[t&1];
  // S group (t&1) builds tile t+1 into P[(t+1)&1] (kf = K(t+1), loaded two
  // phases earlier), then issues LOADK(t+3).
  for (int t = 0; t < 64; ++t) {
    if (isPV) {
      PVLOADV(t);
      PV_PHASE(Psm + (t & 1) * 8192);
    } else if (grp == (t & 1)) {
      if (t + 1 < 64) {
        S_PHASE(Psm + ((t + 1) & 1) * 8192);
        if (t + 3 < 64) LOADK(t + 3);
      }
    }
    __syncthreads();
  }

  // l reduction: butterfly over 32 key-lanes; 2 kq x 2 grp partials per row.
  if (!isPV) {
#pragma unroll
    for (int d = 1; d < 32; d <<= 1)
#pragma unroll
      for (int r = 0; r < 16; ++r) l_part[r] += __shfl_xor(l_part[r], d, 64);
    if (llo == 0) {
#pragma unroll
      for (int r = 0; r < 16; ++r) {
        int row = 32 * rb_s + (r & 3) + 8 * (r >> 2) + 4 * lhi;
        lred[row][2 * kq + grp] = l_part[r];
      }
    }
  }
  __syncthreads();
  if (tid < 64)
    rl_lds[tid] = 1.0f / (lred[tid][0] + lred[tid][1] + lred[tid][2] + lred[tid][3]);
  __syncthreads();

  // Epilogue (PV waves): out = gamma * acc/l + x.
  if (isPV) {
    const float g = gamma[0];
    const int c = chhalf * 256 + 32 * w + llo;
#pragma unroll
    for (int ab = 0; ab < 2; ++ab) {
      const f32x16& a = ab ? acc1 : acc0;
#pragma unroll
      for (int gq = 0; gq < 4; ++gq) {
        int qrow = 32 * ab + 8 * gq + 4 * lhi;
        size_t off = ((size_t)batch * CDIM + c) * NPIX + qbase + qrow;
        f32x4 xv = *(const f32x4*)(x + off);
        f32x4 rlv = *(const f32x4*)&rl_lds[qrow];
        f32x4 ov;
#pragma unroll
        for (int jj = 0; jj < 4; ++jj)
          ov[jj] = g * a[4 * gq + jj] * rlv[jj] + xv[jj];
        *(f32x4*)(out + off) = ov;
      }
    }
  }
}

extern "C" void kernel_launch(void* const* d_in, const int* in_sizes, int n_in,
                              void* d_out, int out_size, void* d_ws, size_t ws_size,
                              hipStream_t stream) {
  (void)in_sizes; (void)n_in; (void)out_size; (void)ws_size;
  const float* x     = (const float*)d_in[0];
  const float* Wq    = (const float*)d_in[1];
  const float* bq    = (const float*)d_in[2];
  const float* Wk    = (const float*)d_in[3];
  const float* bk    = (const float*)d_in[4];
  const float* Wv    = (const float*)d_in[5];
  const float* bv    = (const float*)d_in[6];
  const float* gamma = (const float*)d_in[7];
  float* out = (float*)d_out;

  // Workspace layout (bytes): q fp16 0..2M, k-frag fp16 2..4M, v-frag bf16 4..20M.
  char* ws = (char*)d_ws;
  u16* qh = (u16*)(ws);
  u16* kh = (u16*)(ws + (2u << 20));
  u16* vv = (u16*)(ws + (4u << 20));

  proj_kernel<<<dim3(64, 4), 640, 0, stream>>>(x, Wq, bq, Wk, bk, Wv, bv,
                                               qh, kh, vv);
  attn_kernel<<<512, 1024, 0, stream>>>(qh, kh, vv, x, gamma, out);
}

// Round 20
// 182.281 us; speedup vs baseline: 1.0109x; 1.0109x over previous
//
#include <hip/hip_runtime.h>
#include <hip/hip_bf16.h>

typedef unsigned short u16;
typedef float f32x4 __attribute__((ext_vector_type(4)));
typedef float f32x16 __attribute__((ext_vector_type(16)));
typedef __bf16 bf16x8 __attribute__((ext_vector_type(8)));
typedef _Float16 half8 __attribute__((ext_vector_type(8)));
typedef u16 u16x4 __attribute__((ext_vector_type(4)));
typedef u16 u16x8 __attribute__((ext_vector_type(8)));

#define NPIX 4096
#define CDIM 512
#define LOG2E 1.4426950408889634f

static __device__ __forceinline__ u16 f2bf(float f) {
  return __builtin_bit_cast(u16, (__bf16)f);
}
static __device__ __forceinline__ float bf2f(u16 u) {
  unsigned int v = ((unsigned int)u) << 16;
  return __builtin_bit_cast(float, v);
}
static __device__ __forceinline__ u16 f2h(float f) {
  return __builtin_bit_cast(u16, (_Float16)f);
}
static __device__ __forceinline__ f32x16 zero16() {
  f32x16 z;
#pragma unroll
  for (int i = 0; i < 16; ++i) z[i] = 0.0f;
  return z;
}
static __device__ __forceinline__ f32x16 mfma_bf(bf16x8 a, bf16x8 b, f32x16 c) {
  return __builtin_amdgcn_mfma_f32_32x32x16_bf16(a, b, c, 0, 0, 0);
}
static __device__ __forceinline__ f32x16 mfma_h32(half8 a, half8 b, f32x16 c) {
  return __builtin_amdgcn_mfma_f32_32x32x16_f16(a, b, c, 0, 0, 0);
}

// ---------------------------------------------------------------------------
// Kernel 1: fused QKV projection. R20 changes vs R16-R19 (isolated to proj):
// (1) x slab prefetched into registers one slab ahead (issued right after
//     the "xs ready" barrier; the whole MFMA phase covers HBM latency —
//     previously the load sat exposed between barriers);
// (2) xs row stride 36 -> 37: odd multiplier makes the transposed scalar
//     writes ~2-way instead of 8-way ((ci*36)%32 hit only banks {0,16});
//     reads stay conflict-free (5n mod 32 bijective).
// Outputs byte-identical: q fp16 [b][n][64] (log2e), k/v fragment layouts.
// ---------------------------------------------------------------------------
__global__ __launch_bounds__(640, 3) void proj_kernel(
    const float* __restrict__ x,
    const float* __restrict__ Wq, const float* __restrict__ bq,
    const float* __restrict__ Wk, const float* __restrict__ bk,
    const float* __restrict__ Wv, const float* __restrict__ bv,
    u16* __restrict__ qh, u16* __restrict__ kh, u16* __restrict__ vv)
{
  const int b = blockIdx.y;
  const int nbase = blockIdx.x * 64;
  const int tid = threadIdx.x;
  const int w = tid >> 6;
  const int lane = tid & 63;
  const int lhi = lane >> 5, llo = lane & 31;

  __shared__ float xs[64 * 37];  // [n][k] fp32, stride 37 (bank-spread), 9.5 KB

  const float* xb = x + (size_t)b * CDIM * NPIX + nbase;

  const float* wrow[2];
#pragma unroll
  for (int rb = 0; rb < 2; ++rb) {
    int row = 64 * w + 32 * rb + llo;
    wrow[rb] = (row < 64) ? (Wq + (size_t)row * CDIM)
             : (row < 128) ? (Wk + (size_t)(row - 64) * CDIM)
                           : (Wv + (size_t)(row - 128) * CDIM);
  }

  f32x16 acc[2][2];
  acc[0][0] = zero16(); acc[0][1] = zero16();
  acc[1][0] = zero16(); acc[1][1] = zero16();

  const int xr = tid >> 4;              // k-row within slab (0..31)
  const int xc = (tid & 15) << 2;       // n-col base (0..60)
  f32x4 xreg;
  if (tid < 512)
    xreg = *(const f32x4*)&xb[(size_t)xr * NPIX + xc];  // slab 0

  for (int ks2 = 0; ks2 < 16; ++ks2) {
    __syncthreads();   // previous slab's consumers done; xs free
    if (tid < 512) {
#pragma unroll
      for (int d = 0; d < 4; ++d) xs[(xc + d) * 37 + xr] = xreg[d];
    }
    __syncthreads();   // xs ready
    if (ks2 + 1 < 16 && tid < 512)  // prefetch next slab; MFMA phase covers it
      xreg = *(const f32x4*)&xb[(size_t)((ks2 + 1) * 32 + xr) * NPIX + xc];

#pragma unroll
    for (int kk = 0; kk < 2; ++kk) {
      const int ksoff = ks2 * 32 + kk * 16;
      half8 af[2];
#pragma unroll
      for (int rb = 0; rb < 2; ++rb) {
        const float* wp = wrow[rb] + ksoff + 8 * lhi;
        f32x4 w0 = *(const f32x4*)(wp);
        f32x4 w1 = *(const f32x4*)(wp + 4);
#pragma unroll
        for (int j = 0; j < 4; ++j) {
          af[rb][j] = (_Float16)w0[j];
          af[rb][4 + j] = (_Float16)w1[j];
        }
      }
      half8 bfr[2];
#pragma unroll
      for (int cb = 0; cb < 2; ++cb) {
        int n = 32 * cb + llo;
        const float* xp = &xs[n * 37 + kk * 16 + 8 * lhi];
        f32x4 x0 = *(const f32x4*)(xp);
        f32x4 x1 = *(const f32x4*)(xp + 4);
#pragma unroll
        for (int j = 0; j < 4; ++j) {
          bfr[cb][j] = (_Float16)x0[j];
          bfr[cb][4 + j] = (_Float16)x1[j];
        }
      }
#pragma unroll
      for (int rb = 0; rb < 2; ++rb)
#pragma unroll
        for (int cb = 0; cb < 2; ++cb)
          acc[rb][cb] = mfma_h32(af[rb], bfr[cb], acc[rb][cb]);
    }
  }

  // Epilogue: C/D layout col = lane&31 (n), row = (r&3)+8*(r>>2)+4*lhi.
#pragma unroll
  for (int rb = 0; rb < 2; ++rb) {
#pragma unroll
    for (int cb = 0; cb < 2; ++cb) {
      int n = nbase + 32 * cb + llo;
#pragma unroll
      for (int gq = 0; gq < 4; ++gq) {
        int dr0 = 8 * gq + 4 * lhi;
        float vals[4];
#pragma unroll
        for (int jj = 0; jj < 4; ++jj) {
          int Mrow = 64 * w + 32 * rb + dr0 + jj;
          float bias = (Mrow < 64) ? bq[Mrow] : (Mrow < 128) ? bk[Mrow - 64] : bv[Mrow - 128];
          vals[jj] = acc[rb][cb][4 * gq + jj] + bias;
        }
        if (w == 0) {  // q: single fp16, pre-scaled by log2(e); [b][n][64]
          u16x4 hq;
#pragma unroll
          for (int jj = 0; jj < 4; ++jj) hq[jj] = f2h(vals[jj] * LOG2E);
          size_t off = ((size_t)b * NPIX + n) * 64 + 32 * rb + dr0;
          *(u16x4*)(qh + off) = hq;
        } else if (w == 1) {  // k: fp16, fragment layout
          u16x4 hk;
#pragma unroll
          for (int jj = 0; jj < 4; ++jj) hk[jj] = f2h(vals[jj]);
          int T = n >> 7, kq = (n >> 5) & 3, lf = n & 31;
          int sf = 2 * rb + (gq >> 1), lh = gq & 1;
          size_t F = (((size_t)b * 32 + T) * 4 + kq) * 4 + sf;
          *(u16x4*)(kh + F * 512 + (32 * lh + lf) * 8 + 4 * lhi) = hk;
        } else {  // v: bf16, fragment layout
          int T = n >> 7, s = (n >> 4) & 7, lh = (n >> 3) & 1, jn = n & 7;
#pragma unroll
          for (int jj = 0; jj < 4; ++jj) {
            int c = 64 * w - 128 + 32 * rb + dr0 + jj;
            size_t F = ((((size_t)b * 2 + (c >> 8)) * 8 + ((c >> 5) & 7)) * 32 + T) * 8 + s;
            vv[F * 512 + (32 * lh + (c & 31)) * 8 + jn] = f2bf(vals[jj]);
          }
        }
      }
    }
  }
}

// ---------------------------------------------------------------------------
// Kernel 2: attention — R19's validated structure (132.7 µs), one change:
// s_setprio(1) around PV's MFMA cluster (T5). Prerequisite holds here: PV
// and S waves are at genuinely different roles/phases, so the CU scheduler
// can favor the matrix-pipe wave (guide: +4-7% measured on attn).
// ---------------------------------------------------------------------------

#define LOADK(T) do {                                                         \
  size_t F_ = (((size_t)batch * 32 + ((T) >> 1)) * 4                          \
               + (2 * ((T) & 1) + kq)) * 4;                                   \
  const u16* kp_ = kh + F_ * 512 + (size_t)lane * 8;                          \
  _Pragma("unroll") for (int s_ = 0; s_ < 4; ++s_)                            \
    kf[s_] = *(const half8*)(kp_ + s_ * 512);                                 \
} while (0)

// R15/R18's exact S body: Qs slot-major reads, P row-major 128B + (row&7)<<4.
#define S_PHASE(PB) do {                                                      \
  f32x16 sacc_ = zero16();                                                    \
  _Pragma("unroll") for (int s_ = 0; s_ < 4; ++s_) {                          \
    half8 qf_ = *(const half8*)(Qs + (2 * s_ + lhi) * 1024                    \
                                + (32 * rb_s + llo) * 16);                    \
    sacc_ = mfma_h32(qf_, kf[s_], sacc_);                                     \
  }                                                                           \
  _Pragma("unroll") for (int r_ = 0; r_ < 16; ++r_) {                         \
    float p_ = __builtin_amdgcn_exp2f(sacc_[r_]);                             \
    u16 pb_ = f2bf(p_);                                                       \
    l_part[r_] += bf2f(pb_);                                                  \
    int row_ = 32 * rb_s + (r_ & 3) + 8 * (r_ >> 2) + 4 * lhi;                \
    int byt_ = (row_ * 128 + (32 * kq + llo) * 2) ^ ((row_ & 7) << 4);        \
    *(u16*)((PB) + byt_) = pb_;                                               \
  }                                                                           \
} while (0)

// V fragments for 64-key tile T, wave w's 32 channels: 4 x b128, coalesced.
#define PVLOADV(T) do {                                                       \
  size_t F0_ = (size_t)(bc8 + w) * 256                                        \
               + (size_t)(((T) >> 1) * 8 + 4 * ((T) & 1));                    \
  const u16* g_ = vv + F0_ * 512 + (size_t)lane * 8;                          \
  vf[0] = *(const bf16x8*)(g_);                                               \
  vf[1] = *(const bf16x8*)(g_ + 512);                                         \
  vf[2] = *(const bf16x8*)(g_ + 1024);                                        \
  vf[3] = *(const bf16x8*)(g_ + 1536);                                        \
} while (0)

// R15/R18's exact PV P-read body + setprio(1) around the MFMA cluster (T5).
#define PV_PHASE(PB) do {                                                     \
  __builtin_amdgcn_s_setprio(1);                                              \
  _Pragma("unroll") for (int s_ = 0; s_ < 4; ++s_) {                          \
    int by0_ = (llo * 128 + (16 * s_ + 8 * lhi) * 2) ^ ((llo & 7) << 4);      \
    bf16x8 pa0_ = *(const bf16x8*)((PB) + by0_);                              \
    bf16x8 pa1_ = *(const bf16x8*)((PB) + by0_ + 4096);                       \
    acc0 = mfma_bf(pa0_, vf[s_], acc0);                                       \
    acc1 = mfma_bf(pa1_, vf[s_], acc1);                                       \
  }                                                                           \
  __builtin_amdgcn_s_setprio(0);                                              \
} while (0)

__global__ __launch_bounds__(1024) void attn_kernel(
    const u16* __restrict__ qh, const u16* __restrict__ kh,
    const u16* __restrict__ vv,
    const float* __restrict__ x, const float* __restrict__ gamma,
    float* __restrict__ out)
{
  const int bid = blockIdx.x;
  const int sw = ((bid & 7) << 6) | (bid >> 3);  // bijective, 512 = 8*64
  const int batch = sw >> 7;
  const int chhalf = (sw >> 6) & 1;
  const int qbase = (sw & 63) * 64;
  const int tid = threadIdx.x;
  const int w = tid >> 6;             // 0-7 PV; 8-11 S grp0; 12-15 S grp1
  const int lane = tid & 63;
  const int lhi = lane >> 5, llo = lane & 31;
  const bool isPV = (w < 8);
  const int grp = (w >= 12) ? 1 : 0;
  const int swv = (w - 8) & 3;
  const int rb_s = swv & 1;           // S row half (q 0-31 / 32-63)
  const int kq = swv >> 1;            // S key block (0..1) in 64-key tile
  const int bc8 = (batch * 2 + chhalf) * 8;

  __shared__ alignas(16) char Psm[16384];   // 2 x [64 q rows x 128 B] bf16
  __shared__ alignas(16) char Qs[8192];     // [d8][64 q] x 16 B, slot-major
  __shared__ float lred[64][4];
  __shared__ alignas(16) float rl_lds[64];

  f32x16 acc0 = zero16(), acc1 = zero16();
  float l_part[16];
#pragma unroll
  for (int r = 0; r < 16; ++r) l_part[r] = 0.0f;
  half8 kf[4];
  bf16x8 vf[4];

  // Prologue A: grp0 fills Qs + LOADK(0); grp1 LOADK(2).
  if (!isPV) {
    if (grp == 0) {
#pragma unroll
      for (int j = 0; j < 2; ++j) {
        int idx = swv * 128 + j * 64 + lane;   // 0..511
        int d8 = idx & 7, row = idx >> 3;
        *(u16x8*)(Qs + d8 * 1024 + row * 16) =
            *(const u16x8*)(qh + ((size_t)batch * NPIX + qbase + row) * 64 + d8 * 8);
      }
      LOADK(0);
    } else {
      LOADK(2);
    }
  }
  __syncthreads();
  // Prologue B: grp0 builds tile 0 -> P[0] (kf = K(0)), then LOADK(1).
  if (!isPV && grp == 0) { S_PHASE(Psm); LOADK(1); }
  __syncthreads();

  // Main loop: phase t: PV loads V(t) (issue-early) then consumes P[t&1];
  // S group (t&1) builds tile t+1 into P[(t+1)&1] (kf = K(t+1), loaded two
  // phases earlier), then issues LOADK(t+3).
  for (int t = 0; t < 64; ++t) {
    if (isPV) {
      PVLOADV(t);
      PV_PHASE(Psm + (t & 1) * 8192);
    } else if (grp == (t & 1)) {
      if (t + 1 < 64) {
        S_PHASE(Psm + ((t + 1) & 1) * 8192);
        if (t + 3 < 64) LOADK(t + 3);
      }
    }
    __syncthreads();
  }

  // l reduction: butterfly over 32 key-lanes; 2 kq x 2 grp partials per row.
  if (!isPV) {
#pragma unroll
    for (int d = 1; d < 32; d <<= 1)
#pragma unroll
      for (int r = 0; r < 16; ++r) l_part[r] += __shfl_xor(l_part[r], d, 64);
    if (llo == 0) {
#pragma unroll
      for (int r = 0; r < 16; ++r) {
        int row = 32 * rb_s + (r & 3) + 8 * (r >> 2) + 4 * lhi;
        lred[row][2 * kq + grp] = l_part[r];
      }
    }
  }
  __syncthreads();
  if (tid < 64)
    rl_lds[tid] = 1.0f / (lred[tid][0] + lred[tid][1] + lred[tid][2] + lred[tid][3]);
  __syncthreads();

  // Epilogue (PV waves): out = gamma * acc/l + x.
  if (isPV) {
    const float g = gamma[0];
    const int c = chhalf * 256 + 32 * w + llo;
#pragma unroll
    for (int ab = 0; ab < 2; ++ab) {
      const f32x16& a = ab ? acc1 : acc0;
#pragma unroll
      for (int gq = 0; gq < 4; ++gq) {
        int qrow = 32 * ab + 8 * gq + 4 * lhi;
        size_t off = ((size_t)batch * CDIM + c) * NPIX + qbase + qrow;
        f32x4 xv = *(const f32x4*)(x + off);
        f32x4 rlv = *(const f32x4*)&rl_lds[qrow];
        f32x4 ov;
#pragma unroll
        for (int jj = 0; jj < 4; ++jj)
          ov[jj] = g * a[4 * gq + jj] * rlv[jj] + xv[jj];
        *(f32x4*)(out + off) = ov;
      }
    }
  }
}

extern "C" void kernel_launch(void* const* d_in, const int* in_sizes, int n_in,
                              void* d_out, int out_size, void* d_ws, size_t ws_size,
                              hipStream_t stream) {
  (void)in_sizes; (void)n_in; (void)out_size; (void)ws_size;
  const float* x     = (const float*)d_in[0];
  const float* Wq    = (const float*)d_in[1];
  const float* bq    = (const float*)d_in[2];
  const float* Wk    = (const float*)d_in[3];
  const float* bk    = (const float*)d_in[4];
  const float* Wv    = (const float*)d_in[5];
  const float* bv    = (const float*)d_in[6];
  const float* gamma = (const float*)d_in[7];
  float* out = (float*)d_out;

  // Workspace layout (bytes): q fp16 0..2M, k-frag fp16 2..4M, v-frag bf16 4..20M.
  char* ws = (char*)d_ws;
  u16* qh = (u16*)(ws);
  u16* kh = (u16*)(ws + (2u << 20));
  u16* vv = (u16*)(ws + (4u << 20));

  proj_kernel<<<dim3(64, 4), 640, 0, stream>>>(x, Wq, bq, Wk, bk, Wv, bv,
                                               qh, kh, vv);
  attn_kernel<<<512, 1024, 0, stream>>>(qh, kh, vv, x, gamma, out);
}